// Round 10
// baseline (149.107 us; speedup 1.0000x reference)
//
#include <hip/hip_runtime.h>
#include <hip/hip_bf16.h>

// CategorySpecificLinear: out[b,t,h] = sum_d x[b,t,d] * W[cat[b],d,h] + bias[cat[b],h]
// R10: wave tile 64x64 (halves LDS fragment-read traffic vs 64x32), BM=256 /
// BN=128, 512-thread 8-wave blocks, 55KB LDS -> 2 blocks/CU. ALL staging loads
// unconditional (padded slots duplicate slot 0 -> identical results; stores
// predicated) so prefetch registers stay live (R7-R9 predication sank them:
// VGPR 48-52). Native __float2bfloat16 casts. Sorted 8-batch records dealt
// round-robin across XCDs; a record's 8 ntiles pinned to one XCD.

#define NCAT 32
#define DIN  1024
#define DH   1024
#define NBATCH 256
#define TT   32
#define NRECPAD 64     // record slots (multiple of 8); sum ceil(cnt/8) <= 60
#define RSTRIDE 12     // ints per record: cat, nb, b0..b7, pad2

#define BM 256
#define BN 128
#define BK 32
#define LDK 36         // LDS row stride in bf16 elems (BK + 4 pad), 18 dwords
#define NITER (DIN / BK)   // 32
#define NTILES (DH / BN)   // 8

typedef __attribute__((ext_vector_type(4))) float f32x4;
typedef __attribute__((ext_vector_type(8))) short bf16x8;
typedef __attribute__((ext_vector_type(4))) short bf16x4;

__device__ __forceinline__ short f2bf(float f) {
    __hip_bfloat16 h = __float2bfloat16(f);
    return __builtin_bit_cast(short, h);
}

// ---------------------------------------------------------------------------
// Setup: group batches by category into records of <=8, sort by nb desc,
// write to recs[rank]. Rank r runs on XCD r%8 (round-robin deal = LPT-ish).
// ---------------------------------------------------------------------------
__global__ void cat_setup_kernel(const int* __restrict__ cat_ids,
                                 int* __restrict__ recs) {
    __shared__ int cats[NBATCH];
    __shared__ int cnt[NCAT];
    __shared__ int off[NCAT + 1];
    __shared__ int rstart[NCAT + 1];
    __shared__ int blist[NBATCH];
    __shared__ int cbuf[NRECPAD * RSTRIDE];
    __shared__ int nrec_s;
    const int t = threadIdx.x;
    cats[t] = cat_ids[t];
    for (int i = t; i < NRECPAD * RSTRIDE; i += 256) cbuf[i] = 0;
    __syncthreads();
    if (t < NCAT) {
        int c = 0;
        for (int i = 0; i < NBATCH; ++i) c += (cats[i] == t) ? 1 : 0;
        cnt[t] = c;
    }
    __syncthreads();
    if (t == 0) {
        off[0] = 0; rstart[0] = 0;
        for (int c = 0; c < NCAT; ++c) {
            off[c + 1] = off[c] + cnt[c];
            rstart[c + 1] = rstart[c] + (cnt[c] + 7) / 8;
        }
        nrec_s = rstart[NCAT];
    }
    __syncthreads();
    {   // stable scatter: batches grouped by cat
        int c = cats[t], rank = 0;
        for (int i = 0; i < t; ++i) rank += (cats[i] == c) ? 1 : 0;
        blist[off[c] + rank] = t;
    }
    __syncthreads();
    if (t < NCAT) {   // build this cat's records (chunks of 8)
        int base = off[t], rem = cnt[t], k = 0;
        while (rem > 0) {
            int nb = rem < 8 ? rem : 8;
            int* rb = cbuf + (rstart[t] + k) * RSTRIDE;
            rb[0] = t; rb[1] = nb;
            for (int i = 0; i < nb; ++i) rb[2 + i] = blist[base + i];
            for (int i = nb; i < 8; ++i) rb[2 + i] = rb[2];
            base += nb; rem -= nb; ++k;
        }
    }
    __syncthreads();
    for (int i = t; i < NRECPAD * RSTRIDE; i += 256) recs[i] = 0;
    __syncthreads();
    const int nrec = nrec_s;
    if (t < nrec) {   // rank by nb desc (stable), write
        const int mynb = cbuf[t * RSTRIDE + 1];
        int rank = 0;
        for (int i = 0; i < nrec; ++i) {
            const int nbi = cbuf[i * RSTRIDE + 1];
            rank += ((nbi > mynb) || (nbi == mynb && i < t)) ? 1 : 0;
        }
        for (int f = 0; f < RSTRIDE; ++f)
            recs[rank * RSTRIDE + f] = cbuf[t * RSTRIDE + f];
    }
}

// One K-step: convert+stage tile it (UNCONDITIONAL), prefetch tile it+1 into
// the same regs, barrier (lgkm-only drain), fragments + 16 MFMA.
__device__ __forceinline__ void gemm_step(
    f32x4 (&xv)[4], f32x4 (&wv)[2],
    short* xd, short* wd,
    const short* ap, const short* bp,
    const float* xsrc, const float* wsrc,
    int wn4c, int wk2, int it,
    f32x4 (&acc)[4][4]) {

    // X: convert 16 fp32 -> bf16, 4x b64 LDS writes (rows i*8 apart)
#pragma unroll
    for (int i = 0; i < 4; ++i) {
        bf16x4 q;
        q[0] = f2bf(xv[i][0]);
        q[1] = f2bf(xv[i][1]);
        q[2] = f2bf(xv[i][2]);
        q[3] = f2bf(xv[i][3]);
        *(bf16x4*)(xd + i * 8 * LDK) = q;
    }
    // W: pack k-pairs -> 4x b32 writes wt[n][k..k+1]
#pragma unroll
    for (int jx = 0; jx < 4; ++jx) {
        unsigned pk = (unsigned)(unsigned short)f2bf(wv[0][jx]) |
                      ((unsigned)(unsigned short)f2bf(wv[1][jx]) << 16);
        *(unsigned*)(wd + (wn4c + jx) * LDK + wk2) = pk;
    }

    // prefetch tile it+1 into the just-freed registers (unconditional)
    if (it + 1 < NITER) {
        const int k0 = (it + 1) * BK;
#pragma unroll
        for (int i = 0; i < 4; ++i)
            xv[i] = *(const f32x4*)(xsrc + k0 + (size_t)(i * 8) * DIN);
        wv[0] = *(const f32x4*)(wsrc + (size_t)k0 * DH);
        wv[1] = *(const f32x4*)(wsrc + (size_t)(k0 + 1) * DH);
    }

    // drain LDS writes only — prefetch loads stay in flight across the barrier
    asm volatile("s_waitcnt lgkmcnt(0)" ::: "memory");
    __builtin_amdgcn_s_barrier();
    asm volatile("" ::: "memory");

    bf16x8 af[4], bfr[4];
#pragma unroll
    for (int mi = 0; mi < 4; ++mi)
        af[mi] = *(const bf16x8*)(ap + mi * 16 * LDK);
#pragma unroll
    for (int ni = 0; ni < 4; ++ni)
        bfr[ni] = *(const bf16x8*)(bp + ni * 16 * LDK);

#pragma unroll
    for (int mi = 0; mi < 4; ++mi)
#pragma unroll
        for (int ni = 0; ni < 4; ++ni)
            acc[mi][ni] = __builtin_amdgcn_mfma_f32_16x16x32_bf16(
                af[mi], bfr[ni], acc[mi][ni], 0, 0, 0);
    // next step writes the other LDS buffer; buffer reuse two steps ahead is
    // ordered by the next barrier's preceding lgkmcnt(0).
}

// ---------------------------------------------------------------------------
// Grouped GEMM. 512 threads = 8 waves (4m x 2n), wave tile 64x64.
// wg -> (record rank r, ntile j) with all 8 ntiles of r on XCD r%8.
// ---------------------------------------------------------------------------
__global__ __launch_bounds__(512, 4)
void cat_gemm_kernel(const float* __restrict__ x,
                     const float* __restrict__ W,
                     const float* __restrict__ bias,
                     const int* __restrict__ recs,
                     float* __restrict__ out) {
    const int wg  = blockIdx.x;
    const int xcd = wg & 7;
    const int pos = wg >> 3;                // 0..63
    const int j   = pos & 7;                // ntile
    const int r   = (pos >> 3) * 8 + xcd;   // record rank 0..63

    const int* rec = recs + r * RSTRIDE;
    const int cat = rec[0];
    const int nb  = rec[1];
    if (nb == 0) return;
    const int n0 = j * BN;

    __shared__ short xs[2][BM * LDK];   // 36.9 KB
    __shared__ short wt[2][BN * LDK];   // 18.4 KB

    const int t    = threadIdx.x;
    const int lane = t & 63;
    const int w    = t >> 6;     // wave 0..7
    const int wm   = w >> 1;     // 0..3
    const int wn   = w & 1;      // 0..1
    const int fl   = lane & 15;
    const int kb   = lane >> 4;

    // X staging: wave w stages batch slot w (rows i*8 + (lane>>3), k (lane&7)*4)
    const int xrow   = lane >> 3;
    const int xk4    = (lane & 7) * 4;
    const int xbatch = rec[2 + w];           // padded slots duplicate slot 0
    const float* xsrc = x + (size_t)(xbatch * TT + xrow) * DIN + xk4;
    short* xd0 = &xs[0][0] + (w * 32 + xrow) * LDK + xk4;
    short* xd1 = &xs[1][0] + (w * 32 + xrow) * LDK + xk4;

    // W staging: all 512 threads; 2 k-rows (wk2, wk2+1) x 4 cols (wn4c..+3)
    const int wk2  = (t & 15) * 2;           // 0..30
    const int wn4c = (t >> 4) * 4;           // 0..124
    const float* wsrc = W + (size_t)cat * (DIN * DH) + (size_t)wk2 * DH + n0 + wn4c;

    float bv[4];
#pragma unroll
    for (int ni = 0; ni < 4; ++ni)
        bv[ni] = bias[cat * DH + n0 + wn * 64 + ni * 16 + fl];

    f32x4 acc[4][4];
#pragma unroll
    for (int i = 0; i < 4; ++i)
#pragma unroll
        for (int q = 0; q < 4; ++q)
            acc[i][q] = (f32x4){0.f, 0.f, 0.f, 0.f};

    const short* ap0 = &xs[0][0] + (wm * 64 + fl) * LDK + kb * 8;
    const short* ap1 = &xs[1][0] + (wm * 64 + fl) * LDK + kb * 8;
    const short* bp0 = &wt[0][0] + (wn * 64 + fl) * LDK + kb * 8;
    const short* bp1 = &wt[1][0] + (wn * 64 + fl) * LDK + kb * 8;

    // prologue: load K-tile 0 (unconditional)
    f32x4 xv[4], wv[2];
#pragma unroll
    for (int i = 0; i < 4; ++i)
        xv[i] = *(const f32x4*)(xsrc + (size_t)(i * 8) * DIN);
    wv[0] = *(const f32x4*)(wsrc);
    wv[1] = *(const f32x4*)(wsrc + DH);

    for (int it = 0; it < NITER; it += 2) {
        gemm_step(xv, wv, xd0, &wt[0][0], ap0, bp0, xsrc, wsrc,
                  wn4c, wk2, it, acc);
        gemm_step(xv, wv, xd1, &wt[1][0], ap1, bp1, xsrc, wsrc,
                  wn4c, wk2, it + 1, acc);
    }

    // --- epilogue: bias + store rows of real batch slots only ---
#pragma unroll
    for (int mi = 0; mi < 4; ++mi) {
        const int slot = wm * 2 + (mi >> 1);
        if (slot < nb) {
            const int batch = rec[2 + slot];
            const int rb = (mi & 1) * 16 + kb * 4;
#pragma unroll
            for (int jj = 0; jj < 4; ++jj) {
                const int trow = rb + jj;
                float* orow = out + (size_t)(batch * TT + trow) * DH + n0 + wn * 64;
#pragma unroll
                for (int ni = 0; ni < 4; ++ni)
                    orow[ni * 16 + fl] = acc[mi][ni][jj] + bv[ni];
            }
        }
    }
}

extern "C" void kernel_launch(void* const* d_in, const int* in_sizes, int n_in,
                              void* d_out, int out_size, void* d_ws, size_t ws_size,
                              hipStream_t stream) {
    const float* x       = (const float*)d_in[0];
    const int*   cat_ids = (const int*)d_in[1];
    const float* W       = (const float*)d_in[2];
    const float* bias    = (const float*)d_in[3];
    float*       out     = (float*)d_out;
    int*         recs    = (int*)d_ws;

    hipLaunchKernelGGL(cat_setup_kernel, dim3(1), dim3(256), 0, stream,
                       cat_ids, recs);
    hipLaunchKernelGGL(cat_gemm_kernel, dim3(NRECPAD * NTILES), dim3(512),
                       0, stream, x, W, bias, recs, out);
}

// Round 12
// 125.127 us; speedup vs baseline: 1.1916x; 1.1916x over previous
//
#include <hip/hip_runtime.h>
#include <hip/hip_bf16.h>

// CategorySpecificLinear: out[b,t,h] = sum_d x[b,t,d] * W[cat[b],d,h] + bias[cat[b],h]
// R12: 4-wave 256-thread blocks, wave tile 64x64, BM=256 (8-batch records),
// BN=64, LDS 46KB -> 3 independent blocks/CU (cross-block pipe overlap, m114).
// All staging unconditional (no predication -> no load sinking, uniform flow);
// epilogue stores predicated. Distance-1 register prefetch + double-buffered
// LDS + raw s_barrier (lgkm-only drain; loads can't sink across the "memory"
// asm barrier). XCD-pinned sorted records. setprio around MFMA cluster.

#define NCAT 32
#define DIN  1024
#define DH   1024
#define NBATCH 256
#define TT   32
#define NRECPAD 64     // record slots (multiple of 8); sum ceil(cnt/8) <= 60
#define RSTRIDE 12     // ints per record: cat, nb, b0..b7, pad2

#define BM 256
#define BN 64
#define BK 32
#define LDK 36         // LDS row stride in bf16 elems (BK + 4 pad), 18 dwords
#define NITER (DIN / BK)   // 32
#define NTILES (DH / BN)   // 16

typedef __attribute__((ext_vector_type(4))) float f32x4;
typedef __attribute__((ext_vector_type(8))) short bf16x8;
typedef __attribute__((ext_vector_type(4))) short bf16x4;

__device__ __forceinline__ short f2bf(float f) {
    __hip_bfloat16 h = __float2bfloat16(f);
    return __builtin_bit_cast(short, h);
}

// ---------------------------------------------------------------------------
// Setup: group batches by category into records of <=8, sort by nb desc,
// write to recs[rank]. Rank r runs on XCD r%8 (round-robin deal = LPT-ish).
// ---------------------------------------------------------------------------
__global__ void cat_setup_kernel(const int* __restrict__ cat_ids,
                                 int* __restrict__ recs) {
    __shared__ int cats[NBATCH];
    __shared__ int cnt[NCAT];
    __shared__ int off[NCAT + 1];
    __shared__ int rstart[NCAT + 1];
    __shared__ int blist[NBATCH];
    __shared__ int cbuf[NRECPAD * RSTRIDE];
    __shared__ int nrec_s;
    const int t = threadIdx.x;
    cats[t] = cat_ids[t];
    for (int i = t; i < NRECPAD * RSTRIDE; i += 256) cbuf[i] = 0;
    __syncthreads();
    if (t < NCAT) {
        int c = 0;
        for (int i = 0; i < NBATCH; ++i) c += (cats[i] == t) ? 1 : 0;
        cnt[t] = c;
    }
    __syncthreads();
    if (t == 0) {
        off[0] = 0; rstart[0] = 0;
        for (int c = 0; c < NCAT; ++c) {
            off[c + 1] = off[c] + cnt[c];
            rstart[c + 1] = rstart[c] + (cnt[c] + 7) / 8;
        }
        nrec_s = rstart[NCAT];
    }
    __syncthreads();
    {   // stable scatter: batches grouped by cat
        int c = cats[t], rank = 0;
        for (int i = 0; i < t; ++i) rank += (cats[i] == c) ? 1 : 0;
        blist[off[c] + rank] = t;
    }
    __syncthreads();
    if (t < NCAT) {   // build this cat's records (chunks of 8)
        int base = off[t], rem = cnt[t], k = 0;
        while (rem > 0) {
            int nb = rem < 8 ? rem : 8;
            int* rb = cbuf + (rstart[t] + k) * RSTRIDE;
            rb[0] = t; rb[1] = nb;
            for (int i = 0; i < nb; ++i) rb[2 + i] = blist[base + i];
            for (int i = nb; i < 8; ++i) rb[2 + i] = rb[2];
            base += nb; rem -= nb; ++k;
        }
    }
    __syncthreads();
    for (int i = t; i < NRECPAD * RSTRIDE; i += 256) recs[i] = 0;
    __syncthreads();
    const int nrec = nrec_s;
    if (t < nrec) {   // rank by nb desc (stable), write
        const int mynb = cbuf[t * RSTRIDE + 1];
        int rank = 0;
        for (int i = 0; i < nrec; ++i) {
            const int nbi = cbuf[i * RSTRIDE + 1];
            rank += ((nbi > mynb) || (nbi == mynb && i < t)) ? 1 : 0;
        }
        for (int f = 0; f < RSTRIDE; ++f)
            recs[rank * RSTRIDE + f] = cbuf[t * RSTRIDE + f];
    }
}

// One K-step: convert+stage tile it (unconditional), prefetch tile it+1 into
// the same regs (plain C loads — cannot sink across the "memory" asm barrier),
// lgkm-only drain + s_barrier, fragments + 16 MFMA.
__device__ __forceinline__ void gemm_step(
    f32x4 (&xv)[8], f32x4 (&wv)[2],
    short* xd, short* wd,
    const short* ap, const short* bp,
    const float* xbase, const int (&sb)[8], const float* wsrc,
    int wn4, int wk2, int it,
    f32x4 (&acc)[4][4]) {

    // --- X: convert 8 slots x 4 fp32 -> bf16, 8x b64 LDS writes ---
#pragma unroll
    for (int i = 0; i < 8; ++i) {
        bf16x4 q;
        q[0] = f2bf(xv[i][0]);
        q[1] = f2bf(xv[i][1]);
        q[2] = f2bf(xv[i][2]);
        q[3] = f2bf(xv[i][3]);
        *(bf16x4*)(xd + i * 32 * LDK) = q;
    }
    // --- W: pack k-pairs -> 4x b32 writes wt[n][k..k+1] ---
#pragma unroll
    for (int jx = 0; jx < 4; ++jx) {
        unsigned pk = (unsigned)(unsigned short)f2bf(wv[0][jx]) |
                      ((unsigned)(unsigned short)f2bf(wv[1][jx]) << 16);
        *(unsigned*)(wd + (wn4 + jx) * LDK + wk2) = pk;
    }

    // --- prefetch tile it+1 into the just-freed registers ---
    if (it + 1 < NITER) {
        const int k0 = (it + 1) * BK;
#pragma unroll
        for (int i = 0; i < 8; ++i)
            xv[i] = *(const f32x4*)(xbase + sb[i] + k0);
        wv[0] = *(const f32x4*)(wsrc + (size_t)k0 * DH);
        wv[1] = *(const f32x4*)(wsrc + (size_t)(k0 + 1) * DH);
    }

    // drain LDS writes only — prefetch loads stay in flight across the barrier
    asm volatile("s_waitcnt lgkmcnt(0)" ::: "memory");
    __builtin_amdgcn_s_barrier();
    asm volatile("" ::: "memory");

    // --- fragments + MFMA on tile `it` ---
    bf16x8 af[4], bfr[4];
#pragma unroll
    for (int mi = 0; mi < 4; ++mi)
        af[mi] = *(const bf16x8*)(ap + mi * 16 * LDK);
#pragma unroll
    for (int ni = 0; ni < 4; ++ni)
        bfr[ni] = *(const bf16x8*)(bp + ni * 16 * LDK);

    __builtin_amdgcn_s_setprio(1);
#pragma unroll
    for (int mi = 0; mi < 4; ++mi)
#pragma unroll
        for (int ni = 0; ni < 4; ++ni)
            acc[mi][ni] = __builtin_amdgcn_mfma_f32_16x16x32_bf16(
                af[mi], bfr[ni], acc[mi][ni], 0, 0, 0);
    __builtin_amdgcn_s_setprio(0);
    // next step writes the other LDS buffer; buffer reuse two steps ahead is
    // ordered by the next barrier's preceding lgkmcnt(0).
}

// ---------------------------------------------------------------------------
// Grouped GEMM. 256 threads = 4 waves (4m x 1n), wave tile 64x64.
// wg -> (record rank r, ntile j) with all 16 ntiles of r on XCD r%8.
// ---------------------------------------------------------------------------
__global__ __launch_bounds__(256, 2)
void cat_gemm_kernel(const float* __restrict__ x,
                     const float* __restrict__ W,
                     const float* __restrict__ bias,
                     const int* __restrict__ recs,
                     float* __restrict__ out) {
    const int wg  = blockIdx.x;
    const int xcd = wg & 7;
    const int pos = wg >> 3;                // 0..127
    const int j   = pos & 15;               // ntile
    const int r   = (pos >> 4) * 8 + xcd;   // record rank 0..63

    const int* rec = recs + r * RSTRIDE;
    const int cat = rec[0];
    const int nb  = rec[1];
    if (nb == 0) return;
    const int n0 = j * BN;

    __shared__ short xs[2][BM * LDK];   // 36.9 KB
    __shared__ short wt[2][BN * LDK];   //  9.2 KB   (total 46.1 KB)

    const int t    = threadIdx.x;
    const int lane = t & 63;
    const int w    = t >> 6;     // wave 0..3 (covers rows w*64..w*64+63)
    const int fl   = lane & 15;
    const int kb   = lane >> 4;

    // X staging: thread t stages slot i (i=0..7): batch rec[2+i],
    // row-in-batch t>>3 (0..31), k-chunk (t&7)*4. Per wave-instr: 8 rows x
    // 128B fully coalesced.
    const int xrow = t >> 3;
    const int xk4  = (t & 7) * 4;
    int sb[8];
#pragma unroll
    for (int i = 0; i < 8; ++i)
        sb[i] = rec[2 + i] * (TT * DIN);
    const float* xbase = x + (size_t)xrow * DIN + xk4;
    short* xd0 = &xs[0][0] + xrow * LDK + xk4;
    short* xd1 = &xs[1][0] + xrow * LDK + xk4;

    // W staging: thread -> k-rows wk2,wk2+1; cols wn4..wn4+3 (pack transpose)
    const int wk2 = (t & 15) * 2;        // 0..30
    const int wn4 = (t >> 4) * 4;        // 0..60
    const float* wsrc = W + (size_t)cat * (DIN * DH) + (size_t)wk2 * DH + n0 + wn4;

    float bv[4];
#pragma unroll
    for (int ni = 0; ni < 4; ++ni)
        bv[ni] = bias[cat * DH + n0 + ni * 16 + fl];

    f32x4 acc[4][4];
#pragma unroll
    for (int i = 0; i < 4; ++i)
#pragma unroll
        for (int q = 0; q < 4; ++q)
            acc[i][q] = (f32x4){0.f, 0.f, 0.f, 0.f};

    const short* ap0 = &xs[0][0] + (w * 64 + fl) * LDK + kb * 8;
    const short* ap1 = &xs[1][0] + (w * 64 + fl) * LDK + kb * 8;
    const short* bp0 = &wt[0][0] + fl * LDK + kb * 8;
    const short* bp1 = &wt[1][0] + fl * LDK + kb * 8;

    // prologue: load K-tile 0 (unconditional)
    f32x4 xv[8], wv[2];
#pragma unroll
    for (int i = 0; i < 8; ++i)
        xv[i] = *(const f32x4*)(xbase + sb[i]);
    wv[0] = *(const f32x4*)(wsrc);
    wv[1] = *(const f32x4*)(wsrc + DH);

    for (int it = 0; it < NITER; it += 2) {
        gemm_step(xv, wv, xd0, &wt[0][0], ap0, bp0,
                  xbase, sb, wsrc, wn4, wk2, it, acc);
        gemm_step(xv, wv, xd1, &wt[1][0], ap1, bp1,
                  xbase, sb, wsrc, wn4, wk2, it + 1, acc);
    }

    // --- epilogue: bias + store rows of real batch slots only ---
#pragma unroll
    for (int mi = 0; mi < 4; ++mi) {
        const int slot = 2 * w + (mi >> 1);
        if (slot < nb) {
            const int batch = rec[2 + slot];
            const int rb = (mi & 1) * 16 + kb * 4;
#pragma unroll
            for (int jj = 0; jj < 4; ++jj) {
                const int trow = rb + jj;
                float* orow = out + (size_t)(batch * TT + trow) * DH + n0;
#pragma unroll
                for (int ni = 0; ni < 4; ++ni)
                    orow[ni * 16 + fl] = acc[mi][ni][jj] + bv[ni];
            }
        }
    }
}

extern "C" void kernel_launch(void* const* d_in, const int* in_sizes, int n_in,
                              void* d_out, int out_size, void* d_ws, size_t ws_size,
                              hipStream_t stream) {
    const float* x       = (const float*)d_in[0];
    const int*   cat_ids = (const int*)d_in[1];
    const float* W       = (const float*)d_in[2];
    const float* bias    = (const float*)d_in[3];
    float*       out     = (float*)d_out;
    int*         recs    = (int*)d_ws;

    hipLaunchKernelGGL(cat_setup_kernel, dim3(1), dim3(256), 0, stream,
                       cat_ids, recs);
    hipLaunchKernelGGL(cat_gemm_kernel, dim3(NRECPAD * NTILES), dim3(256),
                       0, stream, x, W, bias, recs, out);
}